// Round 1
// baseline (2596.297 us; speedup 1.0000x reference)
//
#include <hip/hip_runtime.h>
#include <math.h>

namespace {

constexpr int T_STEPS = 512;
constexpr int F_IN    = 25;
constexpr int H_DIM   = 64;
constexpr int G_DIM   = 256;   // 4*H
constexpr int KW      = 92;    // 25 x-weights | 64 h-weights | 1 fused bias | 2 pad
constexpr int TILE_B  = 16;
constexpr int NTHR    = 256;

__device__ __forceinline__ float sigmoid_f(float x) {
    return 1.0f / (1.0f + __expf(-x));
}
__device__ __forceinline__ float tanh_f(float x) {
    // NaN-safe tanh via exp of negative magnitude
    float e = __expf(-2.0f * fabsf(x));
    float r = (1.0f - e) / (1.0f + e);
    return copysignf(r, x);
}

__global__ __launch_bounds__(NTHR)
void lstm_fused(const float* __restrict__ x,     // [B, T, F]
                const float* __restrict__ Wx_w,  // [G, F]
                const float* __restrict__ Wx_b,  // [G]
                const float* __restrict__ Wh_w,  // [G, H]
                const float* __restrict__ Wh_b,  // [G]
                const float* __restrict__ fc_w,  // [H]
                const float* __restrict__ fc_b,  // [1]
                float* __restrict__ out)         // [B]
{
    extern __shared__ float smem[];
    float* w = smem;                   // [G_DIM][KW] combined weights
    float* v = smem + G_DIM * KW;      // [TILE_B][KW] per-row input vector: x | h | 1 | 0,0

    const int tid   = threadIdx.x;
    const int lane  = tid & 63;        // unit u
    const int wv    = tid >> 6;        // wave 0..3
    const int rbase = wv * 4;          // local row base for this wave
    const int row0  = blockIdx.x * TILE_B;

    // ---- build combined weight matrix: w[col][k], col = gate*64 + u ----
    {
        const int col = tid;
        float* wc = w + col * KW;
        #pragma unroll
        for (int f = 0; f < F_IN; ++f) wc[f] = Wx_w[col * F_IN + f];
        #pragma unroll
        for (int j = 0; j < H_DIM; ++j) wc[F_IN + j] = Wh_w[col * H_DIM + j];
        wc[F_IN + H_DIM]     = Wx_b[col] + Wh_b[col];  // fused bias, multiplies v[89]=1
        wc[F_IN + H_DIM + 1] = 0.0f;
        wc[F_IN + H_DIM + 2] = 0.0f;
    }
    // ---- init v: h = 0, bias-one slot, pads ----
    for (int s = tid; s < TILE_B * KW; s += NTHR) {
        int k = s % KW;
        v[s] = (k == F_IN + H_DIM) ? 1.0f : 0.0f;
    }
    __syncthreads();
    // ---- load x[t=0] ----
    for (int s = tid; s < TILE_B * F_IN; s += NTHR) {
        int r = s / F_IN, f = s % F_IN;
        v[r * KW + f] = x[((size_t)(row0 + r) * T_STEPS + 0) * F_IN + f];
    }
    __syncthreads();

    const float fcw = fc_w[lane];
    float c[4] = {0.f, 0.f, 0.f, 0.f};

    for (int t = 0; t < T_STEPS; ++t) {
        // ---- prefetch x[t+1] into registers (latency hides under compute) ----
        float xp0 = 0.f, xp1 = 0.f;
        const int s0 = tid;             // always < 400
        const int s1 = tid + NTHR;
        if (t + 1 < T_STEPS) {
            xp0 = x[((size_t)(row0 + s0 / F_IN) * T_STEPS + (t + 1)) * F_IN + (s0 % F_IN)];
            if (s1 < TILE_B * F_IN)
                xp1 = x[((size_t)(row0 + s1 / F_IN) * T_STEPS + (t + 1)) * F_IN + (s1 % F_IN)];
        }

        // ---- z[r][g*64+lane] for r=0..3 (this wave's rows), g=0..3 ----
        float acc[4][4];
        #pragma unroll
        for (int r = 0; r < 4; ++r)
            #pragma unroll
            for (int g = 0; g < 4; ++g) acc[r][g] = 0.0f;

        #pragma unroll
        for (int k4 = 0; k4 < KW / 4; ++k4) {
            float4 vv[4];
            #pragma unroll
            for (int r = 0; r < 4; ++r)
                vv[r] = *reinterpret_cast<const float4*>(v + (rbase + r) * KW + 4 * k4);
            #pragma unroll
            for (int g = 0; g < 4; ++g) {
                float4 ww = *reinterpret_cast<const float4*>(w + (g * 64 + lane) * KW + 4 * k4);
                #pragma unroll
                for (int r = 0; r < 4; ++r) {
                    acc[r][g] = fmaf(vv[r].x, ww.x, acc[r][g]);
                    acc[r][g] = fmaf(vv[r].y, ww.y, acc[r][g]);
                    acc[r][g] = fmaf(vv[r].z, ww.z, acc[r][g]);
                    acc[r][g] = fmaf(vv[r].w, ww.w, acc[r][g]);
                }
            }
        }

        // ---- gates (split order: i, f, g, o) ----
        float hnew[4];
        #pragma unroll
        for (int r = 0; r < 4; ++r) {
            float ig = sigmoid_f(acc[r][0]);
            float fg = sigmoid_f(acc[r][1]);
            float gg = tanh_f(acc[r][2]);
            float og = sigmoid_f(acc[r][3]);
            float cn = fmaf(fg, c[r], ig * gg);
            c[r] = cn;
            hnew[r] = og * tanh_f(cn);
        }

        __syncthreads();   // everyone done reading v
        #pragma unroll
        for (int r = 0; r < 4; ++r)
            v[(rbase + r) * KW + F_IN + lane] = hnew[r];
        if (t + 1 < T_STEPS) {
            v[(s0 / F_IN) * KW + (s0 % F_IN)] = xp0;
            if (s1 < TILE_B * F_IN)
                v[(s1 / F_IN) * KW + (s1 % F_IN)] = xp1;
        }
        __syncthreads();   // h/x visible for next step
    }

    // ---- epilogue: logits = h_last @ fc_w.T + fc_b ----
    #pragma unroll
    for (int r = 0; r < 4; ++r) {
        float p = v[(rbase + r) * KW + F_IN + lane] * fcw;
        #pragma unroll
        for (int off = 32; off > 0; off >>= 1)
            p += __shfl_down(p, off);
        if (lane == 0) out[row0 + rbase + r] = p + fc_b[0];
    }
}

} // namespace

extern "C" void kernel_launch(void* const* d_in, const int* in_sizes, int n_in,
                              void* d_out, int out_size, void* d_ws, size_t ws_size,
                              hipStream_t stream) {
    const float* x    = (const float*)d_in[0];
    // d_in[1] = mask: all-ones and use_masked_last=False -> unused
    const float* Wx_w = (const float*)d_in[2];
    const float* Wx_b = (const float*)d_in[3];
    const float* Wh_w = (const float*)d_in[4];
    const float* Wh_b = (const float*)d_in[5];
    const float* fc_w = (const float*)d_in[6];
    const float* fc_b = (const float*)d_in[7];
    float* out = (float*)d_out;

    const int B    = out_size;            // 4096
    const int grid = B / TILE_B;          // 256 blocks, 1 per CU
    const size_t smem = (size_t)(G_DIM * KW + TILE_B * KW) * sizeof(float); // ~100 KB

    hipFuncSetAttribute((const void*)lstm_fused,
                        hipFuncAttributeMaxDynamicSharedMemorySize, (int)smem);
    lstm_fused<<<grid, NTHR, smem, stream>>>(x, Wx_w, Wx_b, Wh_w, Wh_b, fc_w, fc_b, out);
}

// Round 2
// 499.485 us; speedup vs baseline: 5.1979x; 5.1979x over previous
//
#include <hip/hip_runtime.h>
#include <math.h>

namespace {

constexpr int TSTEPS = 512;
constexpr int F_IN   = 25;
constexpr int H_DIM  = 64;
constexpr int TILE_B = 16;
constexpr int NTHR   = 256;
// K layout: [0,25) = x, [25,89) = h, 89 = bias-one, [90,96) = zero pad
// A-fragment buffer: [2 bufs][3 ksteps][64 lanes][8 bf16], fragment-ordered:
//   slot (s, lane, j) holds A[row = lane&15][k = s*32 + (lane>>4)*8 + j]

typedef __attribute__((ext_vector_type(8))) short bf16x8;
typedef __attribute__((ext_vector_type(4))) float f32x4;

__device__ __forceinline__ short f2bf(float f) {  // round-to-nearest-even
    unsigned u = __float_as_uint(f);
    unsigned r = (u + 0x7FFFu + ((u >> 16) & 1u)) >> 16;
    return (short)r;
}
__device__ __forceinline__ float bf2f(short s) {
    return __uint_as_float(((unsigned)(unsigned short)s) << 16);
}
__device__ __forceinline__ float sigmoid_f(float x) {
    return 1.0f / (1.0f + __expf(-x));
}
__device__ __forceinline__ float tanh_f(float x) {
    float e = __expf(-2.0f * fabsf(x));
    float r = (1.0f - e) / (1.0f + e);
    return copysignf(r, x);
}

__global__ __launch_bounds__(NTHR)
void lstm_mfma(const float* __restrict__ x,     // [B, T, F]
               const float* __restrict__ Wx_w,  // [256, 25]
               const float* __restrict__ Wx_b,  // [256]
               const float* __restrict__ Wh_w,  // [256, 64]
               const float* __restrict__ Wh_b,  // [256]
               const float* __restrict__ fc_w,  // [64]
               const float* __restrict__ fc_b,  // [1]
               float* __restrict__ out)         // [B]
{
    __shared__ short a_buf[2][3][64][8];   // 6144 B
    __shared__ float red[4][16];

    const int tid  = threadIdx.x;
    const int l    = tid & 63;
    const int wv   = tid >> 6;       // wave id: owns units [wv*16, wv*16+16) x 4 gates
    const int lrow = l & 15;
    const int lhi  = l >> 4;
    const int row0 = blockIdx.x * TILE_B;

    // ---- W^T B-fragments (hi/lo split) into registers: 24 frags = 96 VGPR ----
    bf16x8 w_hi[4][3], w_lo[4][3];
    #pragma unroll
    for (int g = 0; g < 4; ++g) {
        const int col = g * 64 + wv * 16 + lrow;   // gate-col this lane serves
        #pragma unroll
        for (int s = 0; s < 3; ++s) {
            bf16x8 hi, lo;
            #pragma unroll
            for (int j = 0; j < 8; ++j) {
                const int k = s * 32 + lhi * 8 + j;
                float val;
                if (k < F_IN)           val = Wx_w[col * F_IN + k];
                else if (k < 89)        val = Wh_w[col * H_DIM + (k - F_IN)];
                else if (k == 89)       val = Wx_b[col] + Wh_b[col];   // fused bias
                else                    val = 0.0f;
                const short h16 = f2bf(val);
                hi[j] = h16;
                lo[j] = f2bf(val - bf2f(h16));
            }
            w_hi[g][s] = hi;
            w_lo[g][s] = lo;
        }
    }

    // ---- init a_buf: zeros, bias-one at k==89 (both buffers) ----
    for (int idx = tid; idx < 2 * 3 * 64 * 8; idx += NTHR) {
        const int j    = idx & 7;
        const int lane = (idx >> 3) & 63;
        const int s    = (idx >> 9) % 3;
        const int k    = s * 32 + (lane >> 4) * 8 + j;
        ((short*)a_buf)[idx] = (k == 89) ? (short)0x3F80 : (short)0;
    }
    __syncthreads();

    // ---- per-thread x slot mapping (constant across steps) ----
    // element e -> (row = e/25, f = e%25); slot: s=0, lane' = row | ((f>>3)<<4), j = f&7
    const int xrow0 = tid / F_IN,          xf0 = tid % F_IN;           // e0 = tid (<400 always)
    const int xrow1 = (tid + 256) / F_IN,  xf1 = (tid + 256) % F_IN;   // e1 valid iff tid<144
    const float* xp0 = x + (size_t)(row0 + xrow0) * TSTEPS * F_IN + xf0;
    const float* xp1 = x + (size_t)(row0 + (tid < 144 ? xrow1 : 0)) * TSTEPS * F_IN + xf1;
    const int xoff0 = ((xrow0 | ((xf0 >> 3) << 4)) * 8) + (xf0 & 7);
    const int xoff1 = ((xrow1 | ((xf1 >> 3) << 4)) * 8) + (xf1 & 7);
    short* const abase = &a_buf[0][0][0][0];

    // x[t=0] into buffer 0
    abase[xoff0] = f2bf(xp0[0]);
    if (tid < 144) abase[xoff1] = f2bf(xp1[0]);
    __syncthreads();

    // ---- h-write slot mapping (constant): k = 25 + unit ----
    const int unit  = wv * 16 + lrow;
    const int kh    = F_IN + unit;
    const int sh    = kh >> 5;
    const int hbank = ((kh >> 3) & 3) << 4;
    const int jh    = kh & 7;

    const float fcw = fc_w[unit];
    float c[4] = {0.f, 0.f, 0.f, 0.f};
    float hq[4] = {0.f, 0.f, 0.f, 0.f};

    for (int t = 0; t < TSTEPS; ++t) {
        const int p  = t & 1;
        const int pn = p ^ 1;

        // prefetch x[t+1] (latency hides under MFMA + gates)
        float xv0 = 0.f, xv1 = 0.f;
        if (t + 1 < TSTEPS) {
            xv0 = xp0[(t + 1) * F_IN];
            if (tid < 144) xv1 = xp1[(t + 1) * F_IN];
        }

        // A fragments (conflict-free b128, all waves broadcast-read same region)
        bf16x8 a0 = *(const bf16x8*)&a_buf[p][0][l][0];
        bf16x8 a1 = *(const bf16x8*)&a_buf[p][1][l][0];
        bf16x8 a2 = *(const bf16x8*)&a_buf[p][2][l][0];

        // z = v @ W^T  (hi + lo products), acc[g][q] = z[lhi*4+q][g*64+unit]
        f32x4 acc[4];
        #pragma unroll
        for (int g = 0; g < 4; ++g) {
            f32x4 a = {0.f, 0.f, 0.f, 0.f};
            a = __builtin_amdgcn_mfma_f32_16x16x32_bf16(a0, w_hi[g][0], a, 0, 0, 0);
            a = __builtin_amdgcn_mfma_f32_16x16x32_bf16(a0, w_lo[g][0], a, 0, 0, 0);
            a = __builtin_amdgcn_mfma_f32_16x16x32_bf16(a1, w_hi[g][1], a, 0, 0, 0);
            a = __builtin_amdgcn_mfma_f32_16x16x32_bf16(a1, w_lo[g][1], a, 0, 0, 0);
            a = __builtin_amdgcn_mfma_f32_16x16x32_bf16(a2, w_hi[g][2], a, 0, 0, 0);
            a = __builtin_amdgcn_mfma_f32_16x16x32_bf16(a2, w_lo[g][2], a, 0, 0, 0);
            acc[g] = a;
        }

        // gates (split order i,f,g,o) + c/h update + h -> a_buf[pn]
        short* const hdst = &a_buf[pn][sh][0][0];
        #pragma unroll
        for (int q = 0; q < 4; ++q) {
            const float ig = sigmoid_f(acc[0][q]);
            const float fg = sigmoid_f(acc[1][q]);
            const float gg = tanh_f(acc[2][q]);
            const float og = sigmoid_f(acc[3][q]);
            const float cn = fmaf(fg, c[q], ig * gg);
            c[q] = cn;
            const float hv = og * tanh_f(cn);
            hq[q] = hv;
            hdst[(hbank + lhi * 4 + q) * 8 + jh] = f2bf(hv);
        }

        // x[t+1] -> a_buf[pn]
        if (t + 1 < TSTEPS) {
            short* const xdst = abase + pn * (3 * 64 * 8);
            xdst[xoff0] = f2bf(xv0);
            if (tid < 144) xdst[xoff1] = f2bf(xv1);
        }
        __syncthreads();
    }

    // ---- epilogue: logits = h_last @ fc_w + fc_b ----
    #pragma unroll
    for (int q = 0; q < 4; ++q) {
        float pq = hq[q] * fcw;
        pq += __shfl_xor(pq, 1);
        pq += __shfl_xor(pq, 2);
        pq += __shfl_xor(pq, 4);
        pq += __shfl_xor(pq, 8);
        if (lrow == 0) red[wv][lhi * 4 + q] = pq;
    }
    __syncthreads();
    if (tid < TILE_B) {
        out[row0 + tid] = red[0][tid] + red[1][tid] + red[2][tid] + red[3][tid] + fc_b[0];
    }
}

} // namespace

extern "C" void kernel_launch(void* const* d_in, const int* in_sizes, int n_in,
                              void* d_out, int out_size, void* d_ws, size_t ws_size,
                              hipStream_t stream) {
    const float* x    = (const float*)d_in[0];
    // d_in[1] = mask: all-ones, use_masked_last=False -> unused
    const float* Wx_w = (const float*)d_in[2];
    const float* Wx_b = (const float*)d_in[3];
    const float* Wh_w = (const float*)d_in[4];
    const float* Wh_b = (const float*)d_in[5];
    const float* fc_w = (const float*)d_in[6];
    const float* fc_b = (const float*)d_in[7];
    float* out = (float*)d_out;

    const int B    = out_size;        // 4096
    const int grid = B / TILE_B;      // 256 blocks = 1 per CU

    lstm_mfma<<<grid, NTHR, 0, stream>>>(x, Wx_w, Wx_b, Wh_w, Wh_b, fc_w, fc_b, out);
}

// Round 3
// 306.926 us; speedup vs baseline: 8.4590x; 1.6274x over previous
//
#include <hip/hip_runtime.h>
#include <math.h>

namespace {

constexpr int TSTEPS = 512;
constexpr int F_IN   = 25;
constexpr int H_DIM  = 64;
constexpr int TILE_B = 16;
constexpr int NTHR   = 256;
// K layout: [0,25) = x, [25,89) = h, 89 = bias-one, [90,96) = zero pad
// A-fragment buffer: [2 bufs][3 ksteps][64 lanes][8 bf16], fragment-ordered:
//   slot (s, lane, j) holds A[row = lane&15][k = s*32 + (lane>>4)*8 + j]

typedef __attribute__((ext_vector_type(8))) short bf16x8;
typedef __attribute__((ext_vector_type(4))) float f32x4;

__device__ __forceinline__ short f2bf(float f) {  // round-to-nearest-even (setup only)
    unsigned u = __float_as_uint(f);
    unsigned r = (u + 0x7FFFu + ((u >> 16) & 1u)) >> 16;
    return (short)r;
}
__device__ __forceinline__ float bf2f(short s) {
    return __uint_as_float(((unsigned)(unsigned short)s) << 16);
}
__device__ __forceinline__ unsigned cvt_pk_bf16(float lo, float hi) {
    unsigned r;
    asm("v_cvt_pk_bf16_f32 %0, %1, %2" : "=v"(r) : "v"(lo), "v"(hi));
    return r;
}

// Fused LSTM cell: 5 v_exp + 3 v_rcp, no fp32 division.
//   i*g = sign(zg) * (1-eg) / ((1+ei)(1+eg))
//   f   = 1/(1+ef)
//   h   = sign(c') * (1-ec) / ((1+eo)(1+ec))
// Limits: z -> -inf gives e=inf, rcp(inf)=0 -> gate=0 (correct, no NaN).
__device__ __forceinline__ float lstm_cell(float zi, float zf, float zg, float zo, float& c) {
    const float ei = __expf(-zi);
    const float ef = __expf(-zf);
    const float eg = __expf(-2.0f * fabsf(zg));
    const float eo = __expf(-zo);
    const float r1 = __builtin_amdgcn_rcpf((1.0f + ei) * (1.0f + eg));
    const float ig = copysignf((1.0f - eg) * r1, zg);
    const float f  = __builtin_amdgcn_rcpf(1.0f + ef);
    const float cn = fmaf(c, f, ig);
    c = cn;
    const float ec = __expf(-2.0f * fabsf(cn));
    const float r3 = __builtin_amdgcn_rcpf((1.0f + eo) * (1.0f + ec));
    return copysignf((1.0f - ec) * r3, cn);
}

__global__ __launch_bounds__(NTHR)
void lstm_mfma(const float* __restrict__ x,     // [B, T, F]
               const float* __restrict__ Wx_w,  // [256, 25]
               const float* __restrict__ Wx_b,  // [256]
               const float* __restrict__ Wh_w,  // [256, 64]
               const float* __restrict__ Wh_b,  // [256]
               const float* __restrict__ fc_w,  // [64]
               const float* __restrict__ fc_b,  // [1]
               float* __restrict__ out)         // [B]
{
    __shared__ short a_buf[2][3][64][8];   // 6144 B
    __shared__ float red[4][16];

    const int tid  = threadIdx.x;
    const int l    = tid & 63;
    const int wv   = tid >> 6;       // wave id: owns units [wv*16, wv*16+16) x 4 gates
    const int lrow = l & 15;
    const int lhi  = l >> 4;
    const int row0 = blockIdx.x * TILE_B;

    // ---- W^T B-fragments (hi/lo split) into registers: 24 frags = 96 VGPR ----
    bf16x8 w_hi[4][3], w_lo[4][3];
    #pragma unroll
    for (int g = 0; g < 4; ++g) {
        const int col = g * 64 + wv * 16 + lrow;   // gate-col this lane serves
        #pragma unroll
        for (int s = 0; s < 3; ++s) {
            bf16x8 hi, lo;
            #pragma unroll
            for (int j = 0; j < 8; ++j) {
                const int k = s * 32 + lhi * 8 + j;
                float val;
                if (k < F_IN)           val = Wx_w[col * F_IN + k];
                else if (k < 89)        val = Wh_w[col * H_DIM + (k - F_IN)];
                else if (k == 89)       val = Wx_b[col] + Wh_b[col];   // fused bias
                else                    val = 0.0f;
                const short h16 = f2bf(val);
                hi[j] = h16;
                lo[j] = f2bf(val - bf2f(h16));
            }
            w_hi[g][s] = hi;
            w_lo[g][s] = lo;
        }
    }

    // ---- init a_buf: zeros, bias-one at k==89 (both buffers) ----
    for (int idx = tid; idx < 2 * 3 * 64 * 8; idx += NTHR) {
        const int j    = idx & 7;
        const int lane = (idx >> 3) & 63;
        const int s    = (idx >> 9) % 3;
        const int k    = s * 32 + (lane >> 4) * 8 + j;
        ((short*)a_buf)[idx] = (k == 89) ? (short)0x3F80 : (short)0;
    }
    __syncthreads();

    // ---- per-thread x slot mapping (constant across steps) ----
    // element e -> (row = e/25, f = e%25); slot: s=0, lane' = row | ((f>>3)<<4), j = f&7
    const int xrow0 = tid / F_IN,          xf0 = tid % F_IN;           // e0 = tid (<400 always)
    const int xrow1 = (tid + 256) / F_IN,  xf1 = (tid + 256) % F_IN;   // e1 valid iff tid<144
    const float* xq0 = x + (size_t)(row0 + xrow0) * TSTEPS * F_IN + xf0;
    const float* xq1 = x + (size_t)(row0 + (tid < 144 ? xrow1 : 0)) * TSTEPS * F_IN + xf1;
    const int xoff0 = ((xrow0 | ((xf0 >> 3) << 4)) * 8) + (xf0 & 7);
    const int xoff1 = ((xrow1 | ((xf1 >> 3) << 4)) * 8) + (xf1 & 7);
    short* const abase = &a_buf[0][0][0][0];

    // x[t=0] into buffer 0
    abase[xoff0] = f2bf(xq0[0]);
    if (tid < 144) abase[xoff1] = f2bf(xq1[0]);
    __syncthreads();

    // advance prefetch pointers to t=1
    xq0 += F_IN;
    xq1 += F_IN;

    // ---- h-write slot mapping (constant): k = 25 + unit ----
    const int unit  = wv * 16 + lrow;
    const int kh    = F_IN + unit;
    const int sh    = kh >> 5;
    const int hbank = ((kh >> 3) & 3) << 4;
    const int jh    = kh & 7;

    const float fcw = fc_w[unit];
    float c[4] = {0.f, 0.f, 0.f, 0.f};
    float hq[4] = {0.f, 0.f, 0.f, 0.f};

    for (int t = 0; t < TSTEPS; ++t) {
        const int p  = t & 1;
        const int pn = p ^ 1;

        // A fragments (conflict-free b128, all waves broadcast-read same region)
        bf16x8 a0 = *(const bf16x8*)&a_buf[p][0][l][0];
        bf16x8 a1 = *(const bf16x8*)&a_buf[p][1][l][0];
        bf16x8 a2 = *(const bf16x8*)&a_buf[p][2][l][0];

        // prefetch x[t+1] (latency hides under MFMA + gates)
        float xv0 = 0.f, xv1 = 0.f;
        if (t + 1 < TSTEPS) {
            xv0 = xq0[0];
            if (tid < 144) xv1 = xq1[0];
            xq0 += F_IN;
            xq1 += F_IN;
        }

        // z = v @ W^T  (hi + lo products), acc[g][q] = z[lhi*4+q][g*64+unit]
        f32x4 acc[4];
        #pragma unroll
        for (int g = 0; g < 4; ++g) {
            f32x4 a = {0.f, 0.f, 0.f, 0.f};
            a = __builtin_amdgcn_mfma_f32_16x16x32_bf16(a0, w_hi[g][0], a, 0, 0, 0);
            a = __builtin_amdgcn_mfma_f32_16x16x32_bf16(a0, w_lo[g][0], a, 0, 0, 0);
            a = __builtin_amdgcn_mfma_f32_16x16x32_bf16(a1, w_hi[g][1], a, 0, 0, 0);
            a = __builtin_amdgcn_mfma_f32_16x16x32_bf16(a1, w_lo[g][1], a, 0, 0, 0);
            a = __builtin_amdgcn_mfma_f32_16x16x32_bf16(a2, w_hi[g][2], a, 0, 0, 0);
            a = __builtin_amdgcn_mfma_f32_16x16x32_bf16(a2, w_lo[g][2], a, 0, 0, 0);
            acc[g] = a;
        }

        // gates + c/h update
        float h0 = lstm_cell(acc[0][0], acc[1][0], acc[2][0], acc[3][0], c[0]);
        float h1 = lstm_cell(acc[0][1], acc[1][1], acc[2][1], acc[3][1], c[1]);
        float h2 = lstm_cell(acc[0][2], acc[1][2], acc[2][2], acc[3][2], c[2]);
        float h3 = lstm_cell(acc[0][3], acc[1][3], acc[2][3], acc[3][3], c[3]);
        hq[0] = h0; hq[1] = h1; hq[2] = h2; hq[3] = h3;

        // h -> a_buf[pn] as bf16 (packed convert, strided b16 stores)
        const unsigned u01 = cvt_pk_bf16(h0, h1);
        const unsigned u23 = cvt_pk_bf16(h2, h3);
        short* const hdst = &a_buf[pn][sh][0][0] + hbank * 8 + lhi * 32 + jh;
        hdst[0]  = (short)(u01 & 0xffffu);
        hdst[8]  = (short)(u01 >> 16);
        hdst[16] = (short)(u23 & 0xffffu);
        hdst[24] = (short)(u23 >> 16);

        // x[t+1] -> a_buf[pn]
        if (t + 1 < TSTEPS) {
            short* const xdst = abase + pn * (3 * 64 * 8);
            xdst[xoff0] = (short)(cvt_pk_bf16(xv0, xv0) & 0xffffu);
            if (tid < 144) xdst[xoff1] = (short)(cvt_pk_bf16(xv1, xv1) & 0xffffu);
        }
        __syncthreads();
    }

    // ---- epilogue: logits = h_last @ fc_w + fc_b ----
    #pragma unroll
    for (int q = 0; q < 4; ++q) {
        float pq = hq[q] * fcw;
        pq += __shfl_xor(pq, 1);
        pq += __shfl_xor(pq, 2);
        pq += __shfl_xor(pq, 4);
        pq += __shfl_xor(pq, 8);
        if (lrow == 0) red[wv][lhi * 4 + q] = pq;
    }
    __syncthreads();
    if (tid < TILE_B) {
        out[row0 + tid] = red[0][tid] + red[1][tid] + red[2][tid] + red[3][tid] + fc_b[0];
    }
}

} // namespace

extern "C" void kernel_launch(void* const* d_in, const int* in_sizes, int n_in,
                              void* d_out, int out_size, void* d_ws, size_t ws_size,
                              hipStream_t stream) {
    const float* x    = (const float*)d_in[0];
    // d_in[1] = mask: all-ones, use_masked_last=False -> unused
    const float* Wx_w = (const float*)d_in[2];
    const float* Wx_b = (const float*)d_in[3];
    const float* Wh_w = (const float*)d_in[4];
    const float* Wh_b = (const float*)d_in[5];
    const float* fc_w = (const float*)d_in[6];
    const float* fc_b = (const float*)d_in[7];
    float* out = (float*)d_out;

    const int B    = out_size;        // 4096
    const int grid = B / TILE_B;      // 256 blocks = 1 per CU

    lstm_mfma<<<grid, NTHR, 0, stream>>>(x, Wx_w, Wx_b, Wh_w, Wh_b, fc_w, fc_b, out);
}